// Round 5
// baseline (462.909 us; speedup 1.0000x reference)
//
#include <hip/hip_runtime.h>

#define IMG_SIZE 256
#define NPIX (IMG_SIZE * IMG_SIZE)
#define KSEL 5
#define BS 8
#define LL 64
#define LUSED 63          // row l=63's top-k is discarded by the roll — never compute it
#define NTHREADS 256
#define SPLIT 4           // (fallback path) blocks per (b,l) row
#define CHUNK (NPIX / SPLIT)
#define PBINS 256         // R-channel bins for the counting sort
#define NROWS (BS * LUSED)
#define NBPI 64           // sort blocks per image (1024 pixels each)
#define NBLK (BS * NBPI)  // 512 fused blocks; co-resident even at 2 blocks/CU
#define SENTK 0xFFFFFFFFFFFFFFFFULL

typedef unsigned long long ull;

// Control flags for intra-kernel stage gating. Zeroed by a 128 B memset
// before the fused launch (workspace is poisoned by the harness).
struct Ctrl {
    unsigned hist_done[BS];   // blocks of image that finished histogram
    unsigned scan_done[BS];   // image's scan/prefix published
    unsigned scat_done[BS];   // blocks of image that finished scatter
    unsigned rows_done;       // rows completed (last one sums)
    unsigned pad[7];
};

// Branchless sorted-insert: loc[] ascending; bubble key in, evict the max.
__device__ __forceinline__ void sort_insert(ull loc[KSEL], ull key) {
    #pragma unroll
    for (int j = 0; j < KSEL; ++j) {
        const ull a = loc[j];
        const bool lt = key < a;
        loc[j] = lt ? key : a;
        key    = lt ? a : key;
    }
}

// Merge two ascending 5-lists, keep smallest 5 into a (fallback path only).
__device__ __forceinline__ void merge5(ull* a, const ull* b) {
    ull out[KSEL];
    int ia = 0, ib = 0;
    #pragma unroll
    for (int j = 0; j < KSEL; ++j) {
        const ull va = a[ia], vb = b[ib];
        const bool ta = va <= vb;
        out[j] = ta ? va : vb;
        ia += ta ? 1 : 0;
        ib += ta ? 0 : 1;
    }
    #pragma unroll
    for (int j = 0; j < KSEL; ++j) a[j] = out[j];
}

__device__ __forceinline__ ull
pix_key(float r0, float r1, float r2, float c0, float c1, float c2, int pix) {
    // Match numpy f32 exactly: no FMA contraction, ((d0^2+d1^2)+d2^2).
    float d0 = __fsub_rn(r0, c0);
    float d1 = __fsub_rn(r1, c1);
    float d2 = __fsub_rn(r2, c2);
    float s = __fadd_rn(__fadd_rn(__fmul_rn(d0, d0), __fmul_rn(d1, d1)), __fmul_rn(d2, d2));
    // s >= 0 -> uint bit order == float order; low bits = pixel index for
    // jax top_k's lower-index-first tie-break.
    return ((ull)__float_as_uint(s) << 32) | (unsigned int)pix;
}

// Binning formula — identical in hist/scatter; consistent with the bin-edge
// prune (pixels in bin k have r within ~1ulp of [k/256,(k+1)/256), dominated
// by the 0.99/1e-12 slack).
__device__ __forceinline__ int rbin(float r) {
    return min(PBINS - 1, (int)(r * 256.0f));
}

// ---------------------------------------------------------------------------
// FUSED fast path: hist -> (last block per image) scan -> scatter -> rows ->
// (last rows block) sum, all in ONE dispatch. Gating uses device-scope
// release/acquire atomics (G16); 512 blocks x 256 thr are co-resident on
// 256 CUs at any plausible occupancy, so spins cannot deadlock.
// All selection/loss arithmetic is byte-identical to the verified kernels.
// ---------------------------------------------------------------------------
__global__ __launch_bounds__(NTHREADS)
void fused_kernel(const float* __restrict__ preds,
                  const float* __restrict__ imgs,
                  Ctrl* __restrict__ ctrl,
                  unsigned* __restrict__ blockhist,
                  unsigned* __restrict__ cur_base,
                  unsigned* __restrict__ bin_start,
                  float4* __restrict__ sorted,
                  float* __restrict__ bestd,
                  float* __restrict__ out) {
    const int g = blockIdx.x;             // 0..NBLK-1
    const int img = g >> 6;
    const int sub = g & (NBPI - 1);
    const int t = threadIdx.x;
    const int wave = t >> 6;
    const int lane = t & 63;

    __shared__ unsigned sA[PBINS];        // hist h / scan sc / scatter cursor
    __shared__ unsigned sB[PBINS + 1];    // rows: bin_start cache
    __shared__ ull ml[4][KSEL];
    __shared__ float red[NTHREADS];
    __shared__ unsigned sflag;

    // ================= Stage 1: per-block histogram =================
    sA[t] = 0u;
    __syncthreads();
    const float* base = imgs + (size_t)img * 3 * NPIX;
    const int i4 = sub * NTHREADS + t;
    const float4 r4 = ((const float4*)base)[i4];          // R channel, reused in scatter
    atomicAdd(&sA[rbin(r4.x)], 1u);
    atomicAdd(&sA[rbin(r4.y)], 1u);
    atomicAdd(&sA[rbin(r4.z)], 1u);
    atomicAdd(&sA[rbin(r4.w)], 1u);
    __syncthreads();
    blockhist[(size_t)g * PBINS + t] = sA[t];

    __threadfence();                      // release my blockhist row
    if (t == 0) {
        const unsigned old = __hip_atomic_fetch_add(&ctrl->hist_done[img], 1u,
                                                    __ATOMIC_ACQ_REL, __HIP_MEMORY_SCOPE_AGENT);
        sflag = (old == NBPI - 1) ? 1u : 0u;   // last arriving block scans (no spin)
    }
    __syncthreads();

    // ============ Stage 2: per-image scan by the last block ============
    if (sflag) {
        __threadfence();                  // acquire siblings' blockhist
        unsigned total = 0u;              // thread t == bin t
        #pragma unroll 4
        for (int blk = 0; blk < NBPI; ++blk)
            total += blockhist[((size_t)img * NBPI + blk) * PBINS + t];
        __syncthreads();                  // sA free (hist done)
        sA[t] = total;
        __syncthreads();
        for (int st = 1; st < PBINS; st <<= 1) {
            const unsigned v = (t >= st) ? sA[t - st] : 0u;
            __syncthreads();
            sA[t] += v;
            __syncthreads();
        }
        const unsigned start = sA[t] - total;   // exclusive prefix over bins
        bin_start[img * (PBINS + 1) + t] = start;
        if (t == 0) bin_start[img * (PBINS + 1) + PBINS] = NPIX;
        unsigned run = start;
        #pragma unroll 4
        for (int blk = 0; blk < NBPI; ++blk) {  // per-block reservations
            cur_base[((size_t)img * NBPI + blk) * PBINS + t] = run;
            run += blockhist[((size_t)img * NBPI + blk) * PBINS + t];
        }
        __threadfence();                  // release scan outputs
        if (t == 0)
            __hip_atomic_store(&ctrl->scan_done[img], 1u,
                               __ATOMIC_RELEASE, __HIP_MEMORY_SCOPE_AGENT);
    }

    // Gate: my image's scan published.
    if (t == 0) {
        while (__hip_atomic_load(&ctrl->scan_done[img],
                                 __ATOMIC_ACQUIRE, __HIP_MEMORY_SCOPE_AGENT) == 0u)
            __builtin_amdgcn_s_sleep(2);
    }
    __syncthreads();
    __threadfence();                      // acquire scan outputs

    // ================= Stage 3: scatter =================
    sA[t] = cur_base[(size_t)g * PBINS + t];
    __syncthreads();
    const float4 g4 = ((const float4*)(base + NPIX))[i4];
    const float4 b4 = ((const float4*)(base + 2 * NPIX))[i4];
    float4* sp = sorted + (size_t)img * NPIX;
    const unsigned pix0 = (unsigned)(i4 * 4);
    unsigned p;
    p = atomicAdd(&sA[rbin(r4.x)], 1u); sp[p] = make_float4(r4.x, g4.x, b4.x, __uint_as_float(pix0 + 0u));
    p = atomicAdd(&sA[rbin(r4.y)], 1u); sp[p] = make_float4(r4.y, g4.y, b4.y, __uint_as_float(pix0 + 1u));
    p = atomicAdd(&sA[rbin(r4.z)], 1u); sp[p] = make_float4(r4.z, g4.z, b4.z, __uint_as_float(pix0 + 2u));
    p = atomicAdd(&sA[rbin(r4.w)], 1u); sp[p] = make_float4(r4.w, g4.w, b4.w, __uint_as_float(pix0 + 3u));
    __threadfence();                      // release my sorted slice
    if (t == 0)
        __hip_atomic_fetch_add(&ctrl->scat_done[img], 1u,
                               __ATOMIC_RELEASE, __HIP_MEMORY_SCOPE_AGENT);

    // ================= Stage 4: rows (2-phase, verified body) =================
    const int row = g;
    if (row < NROWS) {
        const int b = row / LUSED;
        const int l = row % LUSED;        // storage row; feeds loss row l+1

        // Prelude depends only on inputs -> overlap with the scat gate.
        const int i = l * BS + b;         // scrambled pooled indexing (verified)
        const int pb = i >> 6;
        const int pl = i & 63;
        const float px = preds[pb * (LL * 8) + pl * 8 + 0];
        const float py = preds[pb * (LL * 8) + pl * 8 + 1];
        const float cx = __fsub_rn(__fmul_rn(px, 256.0f), 0.5f);
        const float cy = __fsub_rn(__fmul_rn(py, 256.0f), 0.5f);
        const int ixx = (int)rintf(cx);
        const int iyy = (int)rintf(cy);
        const bool valid = (ixx >= 0) && (ixx < IMG_SIZE) && (iyy >= 0) && (iyy < IMG_SIZE);
        const int ixc = min(max(ixx, 0), IMG_SIZE - 1);
        const int iyc = min(max(iyy, 0), IMG_SIZE - 1);
        const float vmul = valid ? 1.0f : 0.0f;
        const float* imgb = imgs + (size_t)b * 3 * NPIX;
        const float c0 = imgb[0 * NPIX + iyc * IMG_SIZE + ixc] * vmul;
        const float c1 = imgb[1 * NPIX + iyc * IMG_SIZE + ixc] * vmul;
        const float c2 = imgb[2 * NPIX + iyc * IMG_SIZE + ixc] * vmul;

        // Gate: image b fully scattered.
        if (t == 0) {
            while (__hip_atomic_load(&ctrl->scat_done[b],
                                     __ATOMIC_ACQUIRE, __HIP_MEMORY_SCOPE_AGENT) < (unsigned)NBPI)
                __builtin_amdgcn_s_sleep(2);
        }
        __syncthreads();
        __threadfence();                  // acquire sorted/bin_start of image b

        sB[t] = bin_start[b * (PBINS + 1) + t];
        if (t == 0) sB[PBINS] = NPIX;
        const float4* spq = sorted + (size_t)b * NPIX;
        __syncthreads();                  // sB ready

        auto scan_bin = [&](int k, ull (&l5)[KSEL]) {
            const int start = (int)sB[k];
            const int cnt = (int)sB[k + 1] - start;
            for (int o = lane; o < cnt; o += 64) {
                const float4 v = spq[start + o];
                sort_insert(l5, pix_key(v.x, v.y, v.z, c0, c1, c2, (int)__float_as_uint(v.w)));
            }
        };
        auto wave_merge = [&](ull (&l5)[KSEL]) {
            #pragma unroll
            for (int s = 1; s < 64; s <<= 1) {
                ull o[KSEL];
                #pragma unroll
                for (int j = 0; j < KSEL; ++j) o[j] = __shfl_xor(l5[j], s);
                #pragma unroll
                for (int j = 0; j < KSEL; ++j) sort_insert(l5, o[j]);
            }
        };

        ull loc[KSEL];
        #pragma unroll
        for (int j = 0; j < KSEL; ++j) loc[j] = SENTK;

        // Phase 0: central bins {bc-1, bc, bc+1, bc+2} ∩ [0,255].
        const int bc = min(PBINS - 1, max(0, (int)(c0 * 256.0f)));
        const int lo0 = max(bc - 1, 0);
        const int hi0 = min(bc + 2, PBINS - 1);
        {
            ull l5[KSEL];
            #pragma unroll
            for (int j = 0; j < KSEL; ++j) l5[j] = SENTK;
            const int d = (wave == 1) ? -1 : (wave == 2) ? 1 : (wave == 3) ? 2 : 0;
            const int asg = bc + d;
            if (asg >= 0 && asg < PBINS) scan_bin(asg, l5);
            wave_merge(l5);
            if (lane == 0) {
                #pragma unroll
                for (int j = 0; j < KSEL; ++j) ml[wave][j] = l5[j];
            }
            __syncthreads();
            #pragma unroll
            for (int w = 0; w < 4; ++w)
                #pragma unroll
                for (int j = 0; j < KSEL; ++j)
                    sort_insert(loc, ml[w][j]);
        }
        const unsigned thr0 = (unsigned)(loc[KSEL - 1] >> 32);   // f32 bits of s5 / sentinel

        // Range from thr0 (conservative; thr0 >= s5_final => superset => exact).
        int lo = lo0;
        while (lo > 0) {
            const float eL = __fsub_rn(c0, (float)lo * (1.0f / 256.0f));
            const float q = fmaxf(eL * eL * 0.99f - 1e-12f, 0.0f);
            if (__float_as_uint(q) > thr0) break;   // u32 cmp == f32 cmp (both >= 0)
            --lo;
        }
        int hi = hi0;
        while (hi < PBINS - 1) {
            const float eR = __fsub_rn((float)(hi + 1) * (1.0f / 256.0f), c0);
            const float q = fmaxf(eR * eR * 0.99f - 1e-12f, 0.0f);
            if (__float_as_uint(q) > thr0) break;
            ++hi;
        }

        // Phase 1: all remaining bins in one parallel shot.
        const int nL = lo0 - lo;
        const int nR = hi - hi0;
        const int M = nL + nR;
        if (M > 0) {
            ull l5[KSEL];
            #pragma unroll
            for (int j = 0; j < KSEL; ++j) l5[j] = SENTK;
            for (int j = wave; j < M; j += 4) {
                const int bin = (j < nL) ? (lo0 - 1 - j) : (hi0 + 1 + (j - nL));
                scan_bin(bin, l5);
            }
            wave_merge(l5);
            __syncthreads();              // everyone done reading phase-0 ml
            if (lane == 0) {
                #pragma unroll
                for (int j = 0; j < KSEL; ++j) ml[wave][j] = l5[j];
            }
            __syncthreads();
            #pragma unroll
            for (int w = 0; w < 4; ++w)
                #pragma unroll
                for (int j = 0; j < KSEL; ++j)
                    sort_insert(loc, ml[w][j]);
        }

        // Loss element for loss row l+1 (same f32 ops as verified finalize).
        if (t == 0) {
            const float pxl = preds[b * (LL * 8) + (l + 1) * 8 + 0];
            const float pyl = preds[b * (LL * 8) + (l + 1) * 8 + 1];
            float best = 3.4028235e38f;
            #pragma unroll
            for (int k = 0; k < KSEL; ++k) {
                const int ixk = (int)(loc[k] & 0xFFFFFFFFULL);
                const float tx = (float)(ixk & 255) * (1.0f / 256.0f);
                const float ty = (float)(ixk >> 8) * (1.0f / 256.0f);
                const float dx = __fsub_rn(pxl, tx);
                const float dy = __fsub_rn(pyl, ty);
                const float dist = __fadd_rn(__fmul_rn(dx, dx), __fmul_rn(dy, dy));
                best = dist < best ? dist : best;
            }
            bestd[row] = best;
        }

        // ============ Stage 5: deterministic sum by last rows block ============
        __threadfence();                  // release bestd[row]
        if (t == 0) {
            const unsigned old = __hip_atomic_fetch_add(&ctrl->rows_done, 1u,
                                                        __ATOMIC_ACQ_REL, __HIP_MEMORY_SCOPE_AGENT);
            sflag = (old == NROWS - 1) ? 1u : 0u;
        }
        __syncthreads();
        if (sflag) {
            __threadfence();              // acquire all bestd
            float acc = 0.0f;
            for (int q = t; q < NROWS; q += NTHREADS) acc += bestd[q];   // same order as verified sum
            red[t] = acc;
            __syncthreads();
            for (int s = NTHREADS / 2; s > 0; s >>= 1) {
                if (t < s) red[t] += red[t + s];
                __syncthreads();
            }
            if (t == 0) out[0] = red[0] / (float)(BS * (LL - 1));
        }
    }
}

// ---------------------------------------------------------------------------
// Fallback path (verified, 100.4 us): brute-force scan + merge. Used only if
// the workspace is too small for the sort buffers.
// ---------------------------------------------------------------------------
__global__ __launch_bounds__(NTHREADS)
void topk_kernel(const float* __restrict__ preds,
                 const float* __restrict__ imgs,
                 ull* __restrict__ keys_out) {
    const int blk = blockIdx.x;
    const int split = blk & (SPLIT - 1);
    const int row = blk / SPLIT;
    const int b = row / LUSED;
    const int l = row % LUSED;
    const int bid = b * LL + l;
    const int t = threadIdx.x;

    const int i = l * BS + b;
    const int pb = i >> 6;
    const int pl = i & 63;
    const float px = preds[pb * (LL * 8) + pl * 8 + 0];
    const float py = preds[pb * (LL * 8) + pl * 8 + 1];

    const float cx = __fsub_rn(__fmul_rn(px, 256.0f), 0.5f);
    const float cy = __fsub_rn(__fmul_rn(py, 256.0f), 0.5f);
    const int ix = (int)rintf(cx);
    const int iy = (int)rintf(cy);
    const bool valid = (ix >= 0) && (ix < IMG_SIZE) && (iy >= 0) && (iy < IMG_SIZE);
    const int ixc = min(max(ix, 0), IMG_SIZE - 1);
    const int iyc = min(max(iy, 0), IMG_SIZE - 1);
    const float vmul = valid ? 1.0f : 0.0f;

    const float* imgb = imgs + (size_t)b * 3 * NPIX;
    const float c0 = imgb[0 * NPIX + iyc * IMG_SIZE + ixc] * vmul;
    const float c1 = imgb[1 * NPIX + iyc * IMG_SIZE + ixc] * vmul;
    const float c2 = imgb[2 * NPIX + iyc * IMG_SIZE + ixc] * vmul;

    const float4* p0 = (const float4*)(imgb + 0 * NPIX);
    const float4* p1 = (const float4*)(imgb + 1 * NPIX);
    const float4* p2 = (const float4*)(imgb + 2 * NPIX);

    ull loc[KSEL];
    #pragma unroll
    for (int j = 0; j < KSEL; ++j) loc[j] = SENTK;

    const int v0 = split * (CHUNK / 4);
    #pragma unroll 2
    for (int it = 0; it < CHUNK / 4 / NTHREADS; ++it) {
        const int v = v0 + it * NTHREADS + t;
        float4 r0 = p0[v];
        float4 r1 = p1[v];
        float4 r2 = p2[v];
        const int base = v * 4;
        sort_insert(loc, pix_key(r0.x, r1.x, r2.x, c0, c1, c2, base + 0));
        sort_insert(loc, pix_key(r0.y, r1.y, r2.y, c0, c1, c2, base + 1));
        sort_insert(loc, pix_key(r0.z, r1.z, r2.z, c0, c1, c2, base + 2));
        sort_insert(loc, pix_key(r0.w, r1.w, r2.w, c0, c1, c2, base + 3));
    }

    __shared__ ull sk[NTHREADS * KSEL];
    #pragma unroll
    for (int j = 0; j < KSEL; ++j) sk[t * KSEL + j] = loc[j];
    __syncthreads();

    for (int s = NTHREADS / 2; s > 0; s >>= 1) {
        if (t < s) {
            ull a[KSEL], bb[KSEL];
            #pragma unroll
            for (int j = 0; j < KSEL; ++j) { a[j] = sk[t * KSEL + j]; bb[j] = sk[(t + s) * KSEL + j]; }
            merge5(a, bb);
            #pragma unroll
            for (int j = 0; j < KSEL; ++j) sk[t * KSEL + j] = a[j];
        }
        __syncthreads();
    }

    if (t < KSEL) {
        keys_out[((size_t)bid * SPLIT + split) * KSEL + t] = sk[t];
    }
}

__global__ __launch_bounds__(NTHREADS)
void finalize_kernel(const float* __restrict__ preds,
                     const ull* __restrict__ keys,
                     float* __restrict__ out) {
    const int t = threadIdx.x;
    float acc = 0.0f;

    for (int p = t; p < BS * LUSED; p += NTHREADS) {
        const int b = p / LUSED;
        const int l = p % LUSED + 1;
        const float px = preds[b * (LL * 8) + l * 8 + 0];
        const float py = preds[b * (LL * 8) + l * 8 + 1];

        const int srow = b * LL + (l - 1);
        ull loc[KSEL];
        #pragma unroll
        for (int j = 0; j < KSEL; ++j) loc[j] = SENTK;
        #pragma unroll
        for (int s = 0; s < SPLIT; ++s) {
            #pragma unroll
            for (int k = 0; k < KSEL; ++k) {
                sort_insert(loc, keys[((size_t)srow * SPLIT + s) * KSEL + k]);
            }
        }

        float best = 3.4028235e38f;
        #pragma unroll
        for (int k = 0; k < KSEL; ++k) {
            const int ixk = (int)(loc[k] & 0xFFFFFFFFULL);
            const float tx = (float)(ixk & 255) * (1.0f / 256.0f);
            const float ty = (float)(ixk >> 8) * (1.0f / 256.0f);
            const float dx = __fsub_rn(px, tx);
            const float dy = __fsub_rn(py, ty);
            const float dist = __fadd_rn(__fmul_rn(dx, dx), __fmul_rn(dy, dy));
            best = dist < best ? dist : best;
        }
        acc += best;
    }

    __shared__ float red[NTHREADS];
    red[t] = acc;
    __syncthreads();
    for (int s = NTHREADS / 2; s > 0; s >>= 1) {
        if (t < s) red[t] += red[t + s];
        __syncthreads();
    }
    if (t == 0) {
        out[0] = red[0] / (float)(BS * (LL - 1));
    }
}

extern "C" void kernel_launch(void* const* d_in, const int* in_sizes, int n_in,
                              void* d_out, int out_size, void* d_ws, size_t ws_size,
                              hipStream_t stream) {
    const float* preds = (const float*)d_in[0];   // (8, 64, 8) f32
    const float* imgs  = (const float*)d_in[1];   // (8, 3, 256, 256) f32
    float* out = (float*)d_out;                   // scalar f32

    const size_t CTRL_BYTES   = 128;              // sizeof(Ctrl)
    const size_t SORT_BYTES   = (size_t)BS * NPIX * sizeof(float4);                       // 8 MB
    const size_t BSTART_BYTES = ((size_t)BS * (PBINS + 1) * sizeof(unsigned) + 15) & ~(size_t)15;
    const size_t BESTD_BYTES  = ((size_t)NROWS * sizeof(float) + 15) & ~(size_t)15;
    const size_t BHIST_BYTES  = (size_t)NBLK * PBINS * sizeof(unsigned);                  // 512 KB
    const size_t CBASE_BYTES  = (size_t)NBLK * PBINS * sizeof(unsigned);                  // 512 KB
    const size_t TOTAL = CTRL_BYTES + SORT_BYTES + BSTART_BYTES + BESTD_BYTES + BHIST_BYTES + CBASE_BYTES;

    if (ws_size >= TOTAL) {
        char* p = (char*)d_ws;
        Ctrl*     ctrl      = (Ctrl*)p;                p += CTRL_BYTES;
        float4*   sorted    = (float4*)p;              p += SORT_BYTES;
        unsigned* bin_start = (unsigned*)p;            p += BSTART_BYTES;
        float*    bestd     = (float*)p;               p += BESTD_BYTES;
        unsigned* blockhist = (unsigned*)p;            p += BHIST_BYTES;
        unsigned* cur_base  = (unsigned*)p;

        hipMemsetAsync(ctrl, 0, CTRL_BYTES, stream);  // zero stage flags (ws is poisoned)
        fused_kernel<<<dim3(NBLK), dim3(NTHREADS), 0, stream>>>(
            preds, imgs, ctrl, blockhist, cur_base, bin_start, sorted, bestd, out);
    } else {
        // Fallback: verified brute-force path (needs only 80 KB workspace).
        ull* keys = (ull*)d_ws;
        topk_kernel<<<dim3(BS * LUSED * SPLIT), dim3(NTHREADS), 0, stream>>>(preds, imgs, keys);
        finalize_kernel<<<dim3(1), dim3(NTHREADS), 0, stream>>>(preds, keys, out);
    }
}

// Round 6
// 249.829 us; speedup vs baseline: 1.8529x; 1.8529x over previous
//
#include <hip/hip_runtime.h>

#define IMG_SIZE 256
#define NPIX (IMG_SIZE * IMG_SIZE)
#define KSEL 5
#define BS 8
#define LL 64
#define LUSED 63          // row l=63's top-k is discarded by the roll — never compute it
#define NROWS (BS * LUSED)
#define NTHREADS 256      // fallback path block size
#define SPLIT 4           // fallback path blocks per row
#define CHUNK (NPIX / SPLIT)
#define RT 1024           // fast-path threads per row block (16 f4-iters/thread)
#define SENTK 0xFFFFFFFFFFFFFFFFULL

typedef unsigned long long ull;

// Branchless sorted-insert: loc[] ascending; bubble key in, evict the max.
__device__ __forceinline__ void sort_insert(ull loc[KSEL], ull key) {
    #pragma unroll
    for (int j = 0; j < KSEL; ++j) {
        const ull a = loc[j];
        const bool lt = key < a;
        loc[j] = lt ? key : a;
        key    = lt ? a : key;
    }
}

// Merge two ascending 5-lists, keep smallest 5 into a.
__device__ __forceinline__ void merge5(ull* a, const ull* b) {
    ull out[KSEL];
    int ia = 0, ib = 0;
    #pragma unroll
    for (int j = 0; j < KSEL; ++j) {
        const ull va = a[ia], vb = b[ib];
        const bool ta = va <= vb;
        out[j] = ta ? va : vb;
        ia += ta ? 1 : 0;
        ib += ta ? 0 : 1;
    }
    #pragma unroll
    for (int j = 0; j < KSEL; ++j) a[j] = out[j];
}

__device__ __forceinline__ ull
pix_key(float r0, float r1, float r2, float c0, float c1, float c2, int pix) {
    // Match numpy f32 exactly: no FMA contraction, ((d0^2+d1^2)+d2^2).
    float d0 = __fsub_rn(r0, c0);
    float d1 = __fsub_rn(r1, c1);
    float d2 = __fsub_rn(r2, c2);
    float s = __fadd_rn(__fadd_rn(__fmul_rn(d0, d0), __fmul_rn(d1, d1)), __fmul_rn(d2, d2));
    // s >= 0 -> uint bit order == float order; low bits = pixel index for
    // jax top_k's lower-index-first tie-break.
    return ((ull)__float_as_uint(s) << 32) | (unsigned int)pix;
}

// ---------------------------------------------------------------------------
// Fast path: ONE kernel, one block (1024 thr) per (b,l) row, no cross-block
// staging. Exact R-lower-bound filter:
//   SSD_f32 >= d0^2  (rn-adds of nonnegatives never round below an operand)
//   thr (LDS) = min over lanes of lane-local 5th-best >= global s5 always
//   skip iff bits(d0^2) > thr  (strict)  =>  skipped pixel has SSD > s5
// => surviving set is a superset of the top-5; survivors use the verified
// pix_key + per-lane insert + merge5 tree => bit-identical top-5 selection.
// Loss element per block (verified finalize math); deterministic final sum
// (verified sum tree, same order) by the LAST arriving block — per-block
// dirty global data is 4 B, so the agent fences are cheap (unlike staging
// 8 MB through L2, the round-5 fusion failure).
// ---------------------------------------------------------------------------
__global__ __launch_bounds__(RT)
void row_topk_kernel(const float* __restrict__ preds,
                     const float* __restrict__ imgs,
                     unsigned* __restrict__ ctr,
                     float* __restrict__ bestd,
                     float* __restrict__ out) {
    const int row = blockIdx.x;           // 0..NROWS-1
    const int t = threadIdx.x;
    const int lane = t & 63;
    const int b = row / LUSED;
    const int l = row % LUSED;            // storage row; feeds loss row l+1

    __shared__ unsigned thrS;
    __shared__ ull sk[RT * KSEL];         // 40 KB merge scratch
    __shared__ float red[256];
    __shared__ unsigned lastf;

    if (t == 0) { thrS = 0xFFFFFFFFu; lastf = 0u; }

    // Pooled color (verified): scrambled indexing flat i = l*bs + b.
    const int i = l * BS + b;
    const int pb = i >> 6;
    const int pl = i & 63;
    const float px = preds[pb * (LL * 8) + pl * 8 + 0];
    const float py = preds[pb * (LL * 8) + pl * 8 + 1];
    const float cx = __fsub_rn(__fmul_rn(px, 256.0f), 0.5f);
    const float cy = __fsub_rn(__fmul_rn(py, 256.0f), 0.5f);
    const int ix = (int)rintf(cx);
    const int iy = (int)rintf(cy);
    const bool valid = (ix >= 0) && (ix < IMG_SIZE) && (iy >= 0) && (iy < IMG_SIZE);
    const int ixc = min(max(ix, 0), IMG_SIZE - 1);
    const int iyc = min(max(iy, 0), IMG_SIZE - 1);
    const float vmul = valid ? 1.0f : 0.0f;
    const float* imgb = imgs + (size_t)b * 3 * NPIX;
    const float c0 = imgb[0 * NPIX + iyc * IMG_SIZE + ixc] * vmul;
    const float c1 = imgb[1 * NPIX + iyc * IMG_SIZE + ixc] * vmul;
    const float c2 = imgb[2 * NPIX + iyc * IMG_SIZE + ixc] * vmul;

    __syncthreads();                      // thrS/lastf init visible

    ull loc[KSEL];
    #pragma unroll
    for (int j = 0; j < KSEL; ++j) loc[j] = SENTK;

    const float4* rp = (const float4*)imgb;

    // Full evaluation of one pixel (identical math to verified kernels).
    auto feval = [&](float rv, int pix) -> bool {
        const float gv = imgb[NPIX + pix];
        const float bv = imgb[2 * NPIX + pix];
        const ull key = pix_key(rv, gv, bv, c0, c1, c2, pix);
        if (key < loc[KSEL - 1]) { sort_insert(loc, key); return true; }
        return false;
    };
    // Publish a conservative threshold: wave-min of lane 5th-bests, one LDS
    // atomic per wave (avoids same-address LDS atomic storms).
    auto publish = [&]() {
        unsigned m = (unsigned)(loc[KSEL - 1] >> 32);
        #pragma unroll
        for (int s = 1; s < 64; s <<= 1) m = min(m, (unsigned)__shfl_xor((int)m, s));
        if (lane == 0) atomicMin(&thrS, m);
    };

    // Iteration 0: unfiltered bootstrap (4096 px/block), then publish.
    {
        const float4 r4 = rp[t];
        const int pix0 = t * 4;
        feval(r4.x, pix0 + 0);
        feval(r4.y, pix0 + 1);
        feval(r4.z, pix0 + 2);
        feval(r4.w, pix0 + 3);
        publish();
    }
    __syncthreads();                      // tight-ish thr for iteration 1

    #pragma unroll 2
    for (int it = 1; it < NPIX / 4 / RT; ++it) {   // 15 more iterations
        const int i4 = it * RT + t;
        const float4 r4 = rp[i4];
        const unsigned thr = thrS;        // stale read ok: monotone decreasing, conservative
        const int pix0 = i4 * 4;
        bool dirty = false;
        {
            const float d0 = __fsub_rn(r4.x, c0);
            const float q = __fmul_rn(d0, d0);
            if (__float_as_uint(q) <= thr) dirty |= feval(r4.x, pix0 + 0);
        }
        {
            const float d0 = __fsub_rn(r4.y, c0);
            const float q = __fmul_rn(d0, d0);
            if (__float_as_uint(q) <= thr) dirty |= feval(r4.y, pix0 + 1);
        }
        {
            const float d0 = __fsub_rn(r4.z, c0);
            const float q = __fmul_rn(d0, d0);
            if (__float_as_uint(q) <= thr) dirty |= feval(r4.z, pix0 + 2);
        }
        {
            const float d0 = __fsub_rn(r4.w, c0);
            const float q = __fmul_rn(d0, d0);
            if (__float_as_uint(q) <= thr) dirty |= feval(r4.w, pix0 + 3);
        }
        if (__any(dirty)) publish();
    }

    // Block merge: verified merge5 tree over RT per-lane lists.
    #pragma unroll
    for (int j = 0; j < KSEL; ++j) sk[t * KSEL + j] = loc[j];
    __syncthreads();
    for (int s = RT / 2; s > 0; s >>= 1) {
        if (t < s) {
            ull a[KSEL], bb[KSEL];
            #pragma unroll
            for (int j = 0; j < KSEL; ++j) { a[j] = sk[t * KSEL + j]; bb[j] = sk[(t + s) * KSEL + j]; }
            merge5(a, bb);
            #pragma unroll
            for (int j = 0; j < KSEL; ++j) sk[t * KSEL + j] = a[j];
        }
        __syncthreads();
    }

    // Loss element for loss row l+1 (verified finalize math).
    if (t == 0) {
        const float pxl = preds[b * (LL * 8) + (l + 1) * 8 + 0];
        const float pyl = preds[b * (LL * 8) + (l + 1) * 8 + 1];
        float best = 3.4028235e38f;
        #pragma unroll
        for (int k = 0; k < KSEL; ++k) {
            const int ixk = (int)(sk[k] & 0xFFFFFFFFULL);
            const float tx = (float)(ixk & 255) * (1.0f / 256.0f);
            const float ty = (float)(ixk >> 8) * (1.0f / 256.0f);
            const float dx = __fsub_rn(pxl, tx);
            const float dy = __fsub_rn(pyl, ty);
            const float dist = __fadd_rn(__fmul_rn(dx, dx), __fmul_rn(dy, dy));
            best = dist < best ? dist : best;
        }
        bestd[row] = best;
    }

    // Deterministic final sum by the last arriving block (verified tree
    // order: 256-thread strided partials + halving tree).
    __threadfence();                      // release bestd[row] (4 B dirty -> cheap)
    if (t == 0) lastf = (atomicAdd(ctr, 1u) == (unsigned)(NROWS - 1)) ? 1u : 0u;
    __syncthreads();
    if (lastf) {
        __threadfence();                  // acquire all bestd
        float acc = 0.0f;
        if (t < 256) {
            for (int p = t; p < NROWS; p += 256) acc += bestd[p];
            red[t] = acc;
        }
        __syncthreads();
        for (int s = 128; s > 0; s >>= 1) {
            if (t < s) red[t] += red[t + s];
            __syncthreads();
        }
        if (t == 0) out[0] = red[0] / (float)(BS * (LL - 1));
    }
}

// ---------------------------------------------------------------------------
// Fallback path (verified, 100.4 us): brute-force scan + merge. Used only if
// the workspace is too small for the control/bestd buffers.
// ---------------------------------------------------------------------------
__global__ __launch_bounds__(NTHREADS)
void topk_kernel(const float* __restrict__ preds,
                 const float* __restrict__ imgs,
                 ull* __restrict__ keys_out) {
    const int blk = blockIdx.x;
    const int split = blk & (SPLIT - 1);
    const int row = blk / SPLIT;
    const int b = row / LUSED;
    const int l = row % LUSED;
    const int bid = b * LL + l;
    const int t = threadIdx.x;

    const int i = l * BS + b;
    const int pb = i >> 6;
    const int pl = i & 63;
    const float px = preds[pb * (LL * 8) + pl * 8 + 0];
    const float py = preds[pb * (LL * 8) + pl * 8 + 1];

    const float cx = __fsub_rn(__fmul_rn(px, 256.0f), 0.5f);
    const float cy = __fsub_rn(__fmul_rn(py, 256.0f), 0.5f);
    const int ix = (int)rintf(cx);
    const int iy = (int)rintf(cy);
    const bool valid = (ix >= 0) && (ix < IMG_SIZE) && (iy >= 0) && (iy < IMG_SIZE);
    const int ixc = min(max(ix, 0), IMG_SIZE - 1);
    const int iyc = min(max(iy, 0), IMG_SIZE - 1);
    const float vmul = valid ? 1.0f : 0.0f;

    const float* imgb = imgs + (size_t)b * 3 * NPIX;
    const float c0 = imgb[0 * NPIX + iyc * IMG_SIZE + ixc] * vmul;
    const float c1 = imgb[1 * NPIX + iyc * IMG_SIZE + ixc] * vmul;
    const float c2 = imgb[2 * NPIX + iyc * IMG_SIZE + ixc] * vmul;

    const float4* p0 = (const float4*)(imgb + 0 * NPIX);
    const float4* p1 = (const float4*)(imgb + 1 * NPIX);
    const float4* p2 = (const float4*)(imgb + 2 * NPIX);

    ull loc[KSEL];
    #pragma unroll
    for (int j = 0; j < KSEL; ++j) loc[j] = SENTK;

    const int v0 = split * (CHUNK / 4);
    #pragma unroll 2
    for (int it = 0; it < CHUNK / 4 / NTHREADS; ++it) {
        const int v = v0 + it * NTHREADS + t;
        float4 r0 = p0[v];
        float4 r1 = p1[v];
        float4 r2 = p2[v];
        const int base = v * 4;
        sort_insert(loc, pix_key(r0.x, r1.x, r2.x, c0, c1, c2, base + 0));
        sort_insert(loc, pix_key(r0.y, r1.y, r2.y, c0, c1, c2, base + 1));
        sort_insert(loc, pix_key(r0.z, r1.z, r2.z, c0, c1, c2, base + 2));
        sort_insert(loc, pix_key(r0.w, r1.w, r2.w, c0, c1, c2, base + 3));
    }

    __shared__ ull sk[NTHREADS * KSEL];
    #pragma unroll
    for (int j = 0; j < KSEL; ++j) sk[t * KSEL + j] = loc[j];
    __syncthreads();

    for (int s = NTHREADS / 2; s > 0; s >>= 1) {
        if (t < s) {
            ull a[KSEL], bb[KSEL];
            #pragma unroll
            for (int j = 0; j < KSEL; ++j) { a[j] = sk[t * KSEL + j]; bb[j] = sk[(t + s) * KSEL + j]; }
            merge5(a, bb);
            #pragma unroll
            for (int j = 0; j < KSEL; ++j) sk[t * KSEL + j] = a[j];
        }
        __syncthreads();
    }

    if (t < KSEL) {
        keys_out[((size_t)bid * SPLIT + split) * KSEL + t] = sk[t];
    }
}

__global__ __launch_bounds__(NTHREADS)
void finalize_kernel(const float* __restrict__ preds,
                     const ull* __restrict__ keys,
                     float* __restrict__ out) {
    const int t = threadIdx.x;
    float acc = 0.0f;

    for (int p = t; p < BS * LUSED; p += NTHREADS) {
        const int b = p / LUSED;
        const int l = p % LUSED + 1;
        const float px = preds[b * (LL * 8) + l * 8 + 0];
        const float py = preds[b * (LL * 8) + l * 8 + 1];

        const int srow = b * LL + (l - 1);
        ull loc[KSEL];
        #pragma unroll
        for (int j = 0; j < KSEL; ++j) loc[j] = SENTK;
        #pragma unroll
        for (int s = 0; s < SPLIT; ++s) {
            #pragma unroll
            for (int k = 0; k < KSEL; ++k) {
                sort_insert(loc, keys[((size_t)srow * SPLIT + s) * KSEL + k]);
            }
        }

        float best = 3.4028235e38f;
        #pragma unroll
        for (int k = 0; k < KSEL; ++k) {
            const int ixk = (int)(loc[k] & 0xFFFFFFFFULL);
            const float tx = (float)(ixk & 255) * (1.0f / 256.0f);
            const float ty = (float)(ixk >> 8) * (1.0f / 256.0f);
            const float dx = __fsub_rn(px, tx);
            const float dy = __fsub_rn(py, ty);
            const float dist = __fadd_rn(__fmul_rn(dx, dx), __fmul_rn(dy, dy));
            best = dist < best ? dist : best;
        }
        acc += best;
    }

    __shared__ float red[NTHREADS];
    red[t] = acc;
    __syncthreads();
    for (int s = NTHREADS / 2; s > 0; s >>= 1) {
        if (t < s) red[t] += red[t + s];
        __syncthreads();
    }
    if (t == 0) {
        out[0] = red[0] / (float)(BS * (LL - 1));
    }
}

extern "C" void kernel_launch(void* const* d_in, const int* in_sizes, int n_in,
                              void* d_out, int out_size, void* d_ws, size_t ws_size,
                              hipStream_t stream) {
    const float* preds = (const float*)d_in[0];   // (8, 64, 8) f32
    const float* imgs  = (const float*)d_in[1];   // (8, 3, 256, 256) f32
    float* out = (float*)d_out;                   // scalar f32

    const size_t CTRL_BYTES  = 128;
    const size_t BESTD_BYTES = (size_t)NROWS * sizeof(float);

    if (ws_size >= CTRL_BYTES + BESTD_BYTES) {
        unsigned* ctr   = (unsigned*)d_ws;
        float*    bestd = (float*)((char*)d_ws + CTRL_BYTES);
        hipMemsetAsync(ctr, 0, CTRL_BYTES, stream);   // zero the done-counter (ws is poisoned)
        row_topk_kernel<<<dim3(NROWS), dim3(RT), 0, stream>>>(preds, imgs, ctr, bestd, out);
    } else {
        // Fallback: verified brute-force path (needs only 80 KB workspace).
        ull* keys = (ull*)d_ws;
        topk_kernel<<<dim3(NROWS * SPLIT), dim3(NTHREADS), 0, stream>>>(preds, imgs, keys);
        finalize_kernel<<<dim3(1), dim3(NTHREADS), 0, stream>>>(preds, keys, out);
    }
}

// Round 7
// 128.755 us; speedup vs baseline: 3.5953x; 1.9404x over previous
//
#include <hip/hip_runtime.h>

#define IMG_SIZE 256
#define NPIX (IMG_SIZE * IMG_SIZE)
#define KSEL 5
#define BS 8
#define LL 64
#define LUSED 63          // row l=63's top-k is discarded by the roll — never compute it
#define NTHREADS 256
#define SPLIT 4           // blocks per (b,l) row
#define CHUNK (NPIX / SPLIT)      // 16384 pixels per block
#define SENTK 0xFFFFFFFFFFFFFFFFULL

typedef unsigned long long ull;

// Branchless sorted-insert: loc[] ascending; bubble key in, evict the max.
// Static indices only -> stays in VGPRs; no divergence.
__device__ __forceinline__ void sort_insert(ull loc[KSEL], ull key) {
    #pragma unroll
    for (int j = 0; j < KSEL; ++j) {
        const ull a = loc[j];
        const bool lt = key < a;
        loc[j] = lt ? key : a;
        key    = lt ? a : key;
    }
}

// Merge two ascending 5-lists, keep smallest 5 into a.
__device__ __forceinline__ void merge5(ull* a, const ull* b) {
    ull out[KSEL];
    int ia = 0, ib = 0;
    #pragma unroll
    for (int j = 0; j < KSEL; ++j) {
        const ull va = a[ia], vb = b[ib];
        const bool ta = va <= vb;
        out[j] = ta ? va : vb;
        ia += ta ? 1 : 0;
        ib += ta ? 0 : 1;
    }
    #pragma unroll
    for (int j = 0; j < KSEL; ++j) a[j] = out[j];
}

__device__ __forceinline__ ull
pix_key(float r0, float r1, float r2, float c0, float c1, float c2, int pix) {
    // Match numpy f32 exactly: no FMA contraction, ((d0^2+d1^2)+d2^2).
    float d0 = __fsub_rn(r0, c0);
    float d1 = __fsub_rn(r1, c1);
    float d2 = __fsub_rn(r2, c2);
    float s = __fadd_rn(__fadd_rn(__fmul_rn(d0, d0), __fmul_rn(d1, d1)), __fmul_rn(d2, d2));
    // s >= 0 (sum of squares) -> uint bit order == float order; low bits = pixel
    // index gives jax top_k's lower-index-first tie-break.
    return ((ull)__float_as_uint(s) << 32) | (unsigned int)pix;
}

// One block per (b,l,split): scan CHUNK pixels of image b, emit sorted top-5 keys.
// R0 structure + a compute-only gate (loads stay dense/coalesced — the R6
// lesson: gate VALU, never loads):
//   s >= d0^2 in f32 rn (adding nonnegatives never rounds below an operand)
//   thrS = min over published lane 5th-bests >= s5_chunk always
//   reject iff bits(d0^2) > thrS (strict) => s > s5_chunk => not in top-5.
// Survivors use the byte-identical pix_key + per-lane insert + merge5 tree;
// a lane 5-list can never evict a true top-5 key; stale thrS only enlarges
// the evaluated superset => output bit-identical and scheduling-independent.
__global__ __launch_bounds__(NTHREADS)
void topk_kernel(const float* __restrict__ preds,
                 const float* __restrict__ imgs,
                 ull* __restrict__ keys_out) {
    const int blk = blockIdx.x;
    const int split = blk & (SPLIT - 1);
    const int row = blk / SPLIT;         // 0 .. BS*LUSED-1
    const int b = row / LUSED;
    const int l = row % LUSED;
    const int bid = b * LL + l;          // storage row (l < 63)
    const int t = threadIdx.x;
    const int lane = t & 63;

    __shared__ unsigned thrS;
    if (t == 0) thrS = 0xFFFFFFFFu;

    // Scrambled pooled indexing: flat i = l*bs + b; position from preds[i//L, i%L].
    const int i = l * BS + b;
    const int pb = i >> 6;
    const int pl = i & 63;
    const float px = preds[pb * (LL * 8) + pl * 8 + 0];
    const float py = preds[pb * (LL * 8) + pl * 8 + 1];

    // grid_sample nearest, align_corners=False, zeros padding.
    const float cx = __fsub_rn(__fmul_rn(px, 256.0f), 0.5f);
    const float cy = __fsub_rn(__fmul_rn(py, 256.0f), 0.5f);
    const int ix = (int)rintf(cx);       // round half to even == jnp.rint
    const int iy = (int)rintf(cy);
    const bool valid = (ix >= 0) && (ix < IMG_SIZE) && (iy >= 0) && (iy < IMG_SIZE);
    const int ixc = min(max(ix, 0), IMG_SIZE - 1);
    const int iyc = min(max(iy, 0), IMG_SIZE - 1);
    const float vmul = valid ? 1.0f : 0.0f;

    const float* imgb = imgs + (size_t)b * 3 * NPIX;
    const float c0 = imgb[0 * NPIX + iyc * IMG_SIZE + ixc] * vmul;
    const float c1 = imgb[1 * NPIX + iyc * IMG_SIZE + ixc] * vmul;
    const float c2 = imgb[2 * NPIX + iyc * IMG_SIZE + ixc] * vmul;

    const float4* p0 = (const float4*)(imgb + 0 * NPIX);
    const float4* p1 = (const float4*)(imgb + 1 * NPIX);
    const float4* p2 = (const float4*)(imgb + 2 * NPIX);

    __syncthreads();                     // thrS init visible

    ull loc[KSEL];
    #pragma unroll
    for (int j = 0; j < KSEL; ++j) loc[j] = SENTK;

    // CHUNK/4 = 4096 float4s; 16 iterations of 256 threads. Dense 3-plane
    // loads every iteration (coalesced, L2-resident); only the key-build +
    // u64 insert are gated.
    const int v0 = split * (CHUNK / 4);
    #pragma unroll 2
    for (int it = 0; it < CHUNK / 4 / NTHREADS; ++it) {
        const int v = v0 + it * NTHREADS + t;
        float4 r0 = p0[v];
        float4 r1 = p1[v];
        float4 r2 = p2[v];
        const unsigned thr = *(volatile unsigned*)&thrS;   // stale ok: monotone, conservative
        const int base = v * 4;
        bool dirty = false;

        {
            const float d0 = __fsub_rn(r0.x, c0);
            const float q = __fmul_rn(d0, d0);
            if (__float_as_uint(q) <= thr) {
                const ull key = pix_key(r0.x, r1.x, r2.x, c0, c1, c2, base + 0);
                if (key < loc[KSEL - 1]) { sort_insert(loc, key); dirty = true; }
            }
        }
        {
            const float d0 = __fsub_rn(r0.y, c0);
            const float q = __fmul_rn(d0, d0);
            if (__float_as_uint(q) <= thr) {
                const ull key = pix_key(r0.y, r1.y, r2.y, c0, c1, c2, base + 1);
                if (key < loc[KSEL - 1]) { sort_insert(loc, key); dirty = true; }
            }
        }
        {
            const float d0 = __fsub_rn(r0.z, c0);
            const float q = __fmul_rn(d0, d0);
            if (__float_as_uint(q) <= thr) {
                const ull key = pix_key(r0.z, r1.z, r2.z, c0, c1, c2, base + 2);
                if (key < loc[KSEL - 1]) { sort_insert(loc, key); dirty = true; }
            }
        }
        {
            const float d0 = __fsub_rn(r0.w, c0);
            const float q = __fmul_rn(d0, d0);
            if (__float_as_uint(q) <= thr) {
                const ull key = pix_key(r0.w, r1.w, r2.w, c0, c1, c2, base + 3);
                if (key < loc[KSEL - 1]) { sort_insert(loc, key); dirty = true; }
            }
        }

        // Publish: wave-min of lane 5th-best s-bits, one LDS atomic per wave.
        // Rare after warm-up (only when some lane actually inserted).
        if (__any(dirty)) {
            unsigned m = (unsigned)(loc[KSEL - 1] >> 32);
            #pragma unroll
            for (int s = 1; s < 64; s <<= 1)
                m = min(m, (unsigned)__shfl_xor((int)m, s));
            if (lane == 0) atomicMin(&thrS, m);
        }
    }

    // Verified LDS merge tree (byte-identical to R0 baseline).
    __shared__ ull sk[NTHREADS * KSEL];
    #pragma unroll
    for (int j = 0; j < KSEL; ++j) sk[t * KSEL + j] = loc[j];
    __syncthreads();

    for (int s = NTHREADS / 2; s > 0; s >>= 1) {
        if (t < s) {
            ull a[KSEL], bb[KSEL];
            #pragma unroll
            for (int j = 0; j < KSEL; ++j) { a[j] = sk[t * KSEL + j]; bb[j] = sk[(t + s) * KSEL + j]; }
            merge5(a, bb);
            #pragma unroll
            for (int j = 0; j < KSEL; ++j) sk[t * KSEL + j] = a[j];
        }
        __syncthreads();
    }

    if (t < KSEL) {
        keys_out[((size_t)bid * SPLIT + split) * KSEL + t] = sk[t];
    }
}

// Epilogue (verified, unchanged): merge the SPLIT partial top-5s per row, roll
// along L, min positional distance over the 5 selected pixels, mean.
__global__ __launch_bounds__(NTHREADS)
void finalize_kernel(const float* __restrict__ preds,
                     const ull* __restrict__ keys,
                     float* __restrict__ out) {
    const int t = threadIdx.x;
    float acc = 0.0f;

    for (int p = t; p < BS * LUSED; p += NTHREADS) {
        const int b = p / LUSED;
        const int l = p % LUSED + 1;              // loss rows: l = 1..63
        const float px = preds[b * (LL * 8) + l * 8 + 0];
        const float py = preds[b * (LL * 8) + l * 8 + 1];

        // tgt_down[:, l] = tgt[:, l-1]: merge the SPLIT sorted 5-lists of row l-1.
        const int srow = b * LL + (l - 1);
        ull loc[KSEL];
        #pragma unroll
        for (int j = 0; j < KSEL; ++j) loc[j] = SENTK;
        #pragma unroll
        for (int s = 0; s < SPLIT; ++s) {
            #pragma unroll
            for (int k = 0; k < KSEL; ++k) {
                sort_insert(loc, keys[((size_t)srow * SPLIT + s) * KSEL + k]);
            }
        }

        float best = 3.4028235e38f;
        #pragma unroll
        for (int k = 0; k < KSEL; ++k) {
            const int ixk = (int)(loc[k] & 0xFFFFFFFFULL);
            const float tx = (float)(ixk & 255) * (1.0f / 256.0f);   // exact /256
            const float ty = (float)(ixk >> 8) * (1.0f / 256.0f);
            const float dx = __fsub_rn(px, tx);
            const float dy = __fsub_rn(py, ty);
            const float dist = __fadd_rn(__fmul_rn(dx, dx), __fmul_rn(dy, dy));
            best = dist < best ? dist : best;
        }
        acc += best;
    }

    __shared__ float red[NTHREADS];
    red[t] = acc;
    __syncthreads();
    for (int s = NTHREADS / 2; s > 0; s >>= 1) {
        if (t < s) red[t] += red[t + s];
        __syncthreads();
    }
    if (t == 0) {
        out[0] = red[0] / (float)(BS * (LL - 1));
    }
}

extern "C" void kernel_launch(void* const* d_in, const int* in_sizes, int n_in,
                              void* d_out, int out_size, void* d_ws, size_t ws_size,
                              hipStream_t stream) {
    const float* preds = (const float*)d_in[0];   // (8, 64, 8) f32
    const float* imgs  = (const float*)d_in[1];   // (8, 3, 256, 256) f32
    float* out = (float*)d_out;                   // scalar f32
    ull* keys = (ull*)d_ws;                       // 512 * SPLIT * 5 u64 = 80 KB

    topk_kernel<<<dim3(BS * LUSED * SPLIT), dim3(NTHREADS), 0, stream>>>(preds, imgs, keys);
    finalize_kernel<<<dim3(1), dim3(NTHREADS), 0, stream>>>(preds, keys, out);
}

// Round 8
// 96.642 us; speedup vs baseline: 4.7899x; 1.3323x over previous
//
#include <hip/hip_runtime.h>

#define IMG_SIZE 256
#define NPIX (IMG_SIZE * IMG_SIZE)
#define KSEL 5
#define BS 8
#define LL 64
#define LUSED 63          // row l=63's top-k is discarded by the roll — never compute it
#define NTHREADS 256
#define SPLIT 4           // blocks per (b,l) row
#define CHUNK (NPIX / SPLIT)      // 16384 pixels per block
#define QCAP 512          // per-wave candidate queue (u64 keys)
#define SENTK 0xFFFFFFFFFFFFFFFFULL

typedef unsigned long long ull;

// Branchless sorted-insert: loc[] ascending; bubble key in, evict the max.
// Static indices only -> stays in VGPRs; no divergence.
__device__ __forceinline__ void sort_insert(ull loc[KSEL], ull key) {
    #pragma unroll
    for (int j = 0; j < KSEL; ++j) {
        const ull a = loc[j];
        const bool lt = key < a;
        loc[j] = lt ? key : a;
        key    = lt ? a : key;
    }
}

// Merge two ascending 5-lists, keep smallest 5 into a.
__device__ __forceinline__ void merge5(ull* a, const ull* b) {
    ull out[KSEL];
    int ia = 0, ib = 0;
    #pragma unroll
    for (int j = 0; j < KSEL; ++j) {
        const ull va = a[ia], vb = b[ib];
        const bool ta = va <= vb;
        out[j] = ta ? va : vb;
        ia += ta ? 1 : 0;
        ib += ta ? 0 : 1;
    }
    #pragma unroll
    for (int j = 0; j < KSEL; ++j) a[j] = out[j];
}

// Single source of truth for the SSD: match numpy f32 exactly — no FMA
// contraction, ((d0^2+d1^2)+d2^2). Both the bootstrap keys and the steady-path
// gate use THIS function, so gate-s and key-s are bit-identical.
__device__ __forceinline__ float
pix_s(float r0, float r1, float r2, float c0, float c1, float c2) {
    float d0 = __fsub_rn(r0, c0);
    float d1 = __fsub_rn(r1, c1);
    float d2 = __fsub_rn(r2, c2);
    return __fadd_rn(__fadd_rn(__fmul_rn(d0, d0), __fmul_rn(d1, d1)), __fmul_rn(d2, d2));
}

__device__ __forceinline__ ull
pix_key(float r0, float r1, float r2, float c0, float c1, float c2, int pix) {
    // s >= 0 (sum of squares) -> uint bit order == float order; low bits = pixel
    // index gives jax top_k's lower-index-first tie-break.
    const float s = pix_s(r0, r1, r2, c0, c1, c2);
    return ((ull)__float_as_uint(s) << 32) | (unsigned int)pix;
}

// One block per (b,l,split). R7 lesson: lane-granular gating around the insert
// loses to wave divergence (P(any of 64 lanes survives) ~ 1). So the steady
// path has NO insert at all: compute s (9 ops), gate, and push rare survivors
// (p ~ 0.5% with a block-exact bootstrap threshold) to a per-wave LDS queue.
//   thr = 5th-smallest s over the 1024-pixel bootstrap (verified merge5 tree)
//       >= s5_chunk  (5th-smallest over a subset >= over the full set)
//   admit iff bits(s) <= thr  =>  every true top-5 key is in bootstrap ∪ queue
// Each pixel enters exactly once; drained keys are inserted once by one lane;
// the verified merge tree over the union gives the bit-identical top-5.
__global__ __launch_bounds__(NTHREADS)
void topk_kernel(const float* __restrict__ preds,
                 const float* __restrict__ imgs,
                 ull* __restrict__ keys_out) {
    const int blk = blockIdx.x;
    const int split = blk & (SPLIT - 1);
    const int row = blk / SPLIT;         // 0 .. BS*LUSED-1
    const int b = row / LUSED;
    const int l = row % LUSED;
    const int bid = b * LL + l;          // storage row (l < 63)
    const int t = threadIdx.x;
    const int wave = t >> 6;
    const int lane = t & 63;

    __shared__ ull sk[NTHREADS * KSEL];  // merge scratch (10240 B)
    __shared__ ull qq[4][QCAP];          // per-wave candidate queues (16384 B)
    __shared__ unsigned wcnt[4];
    __shared__ unsigned thrsh;

    if (t < 4) wcnt[t] = 0u;

    // Scrambled pooled indexing: flat i = l*bs + b; position from preds[i//L, i%L].
    const int i = l * BS + b;
    const int pb = i >> 6;
    const int pl = i & 63;
    const float px = preds[pb * (LL * 8) + pl * 8 + 0];
    const float py = preds[pb * (LL * 8) + pl * 8 + 1];

    // grid_sample nearest, align_corners=False, zeros padding.
    const float cx = __fsub_rn(__fmul_rn(px, 256.0f), 0.5f);
    const float cy = __fsub_rn(__fmul_rn(py, 256.0f), 0.5f);
    const int ix = (int)rintf(cx);       // round half to even == jnp.rint
    const int iy = (int)rintf(cy);
    const bool valid = (ix >= 0) && (ix < IMG_SIZE) && (iy >= 0) && (iy < IMG_SIZE);
    const int ixc = min(max(ix, 0), IMG_SIZE - 1);
    const int iyc = min(max(iy, 0), IMG_SIZE - 1);
    const float vmul = valid ? 1.0f : 0.0f;

    const float* imgb = imgs + (size_t)b * 3 * NPIX;
    const float c0 = imgb[0 * NPIX + iyc * IMG_SIZE + ixc] * vmul;
    const float c1 = imgb[1 * NPIX + iyc * IMG_SIZE + ixc] * vmul;
    const float c2 = imgb[2 * NPIX + iyc * IMG_SIZE + ixc] * vmul;

    const float4* p0 = (const float4*)(imgb + 0 * NPIX);
    const float4* p1 = (const float4*)(imgb + 1 * NPIX);
    const float4* p2 = (const float4*)(imgb + 2 * NPIX);

    ull loc[KSEL];
    #pragma unroll
    for (int j = 0; j < KSEL; ++j) loc[j] = SENTK;

    const int v0 = split * (CHUNK / 4);

    // ---- Bootstrap: iteration 0 (1024 pixels), unconditional inserts ----
    {
        const int v = v0 + t;
        const float4 r0 = p0[v];
        const float4 r1 = p1[v];
        const float4 r2 = p2[v];
        const int base = v * 4;
        sort_insert(loc, pix_key(r0.x, r1.x, r2.x, c0, c1, c2, base + 0));
        sort_insert(loc, pix_key(r0.y, r1.y, r2.y, c0, c1, c2, base + 1));
        sort_insert(loc, pix_key(r0.z, r1.z, r2.z, c0, c1, c2, base + 2));
        sort_insert(loc, pix_key(r0.w, r1.w, r2.w, c0, c1, c2, base + 3));
    }

    // Block-exact bootstrap threshold via the verified merge5 tree.
    #pragma unroll
    for (int j = 0; j < KSEL; ++j) sk[t * KSEL + j] = loc[j];
    __syncthreads();
    for (int s = NTHREADS / 2; s > 0; s >>= 1) {
        if (t < s) {
            ull a[KSEL], bb[KSEL];
            #pragma unroll
            for (int j = 0; j < KSEL; ++j) { a[j] = sk[t * KSEL + j]; bb[j] = sk[(t + s) * KSEL + j]; }
            merge5(a, bb);
            #pragma unroll
            for (int j = 0; j < KSEL; ++j) sk[t * KSEL + j] = a[j];
        }
        __syncthreads();
    }
    if (t == 0) thrsh = (unsigned)(sk[KSEL - 1] >> 32);   // bits of s5(bootstrap)
    __syncthreads();
    const unsigned thr = thrsh;          // register; no further LDS reads

    // ---- Steady loop: dense loads, 9-op s + gate, rare queue push ----
    #pragma unroll 2
    for (int it = 1; it < CHUNK / 4 / NTHREADS; ++it) {
        // Overflow safety (wave-uniform; never triggers on random data):
        // guarantee room for this iteration's max 256 pushes.
        if (wcnt[wave] + NTHREADS > QCAP) {
            const unsigned n = wcnt[wave];
            for (unsigned o = lane; o < n; o += 64) sort_insert(loc, qq[wave][o]);
            if (lane == 0) wcnt[wave] = 0u;   // wave-lockstep: reads above precede this
        }
        const int v = v0 + it * NTHREADS + t;
        const float4 r0 = p0[v];
        const float4 r1 = p1[v];
        const float4 r2 = p2[v];
        const int base = v * 4;

        const float sx = pix_s(r0.x, r1.x, r2.x, c0, c1, c2);
        const float sy = pix_s(r0.y, r1.y, r2.y, c0, c1, c2);
        const float sz = pix_s(r0.z, r1.z, r2.z, c0, c1, c2);
        const float sw = pix_s(r0.w, r1.w, r2.w, c0, c1, c2);

        if (__float_as_uint(sx) <= thr) {
            const unsigned pos = atomicAdd(&wcnt[wave], 1u);
            qq[wave][pos] = ((ull)__float_as_uint(sx) << 32) | (unsigned)(base + 0);
        }
        if (__float_as_uint(sy) <= thr) {
            const unsigned pos = atomicAdd(&wcnt[wave], 1u);
            qq[wave][pos] = ((ull)__float_as_uint(sy) << 32) | (unsigned)(base + 1);
        }
        if (__float_as_uint(sz) <= thr) {
            const unsigned pos = atomicAdd(&wcnt[wave], 1u);
            qq[wave][pos] = ((ull)__float_as_uint(sz) << 32) | (unsigned)(base + 2);
        }
        if (__float_as_uint(sw) <= thr) {
            const unsigned pos = atomicAdd(&wcnt[wave], 1u);
            qq[wave][pos] = ((ull)__float_as_uint(sw) << 32) | (unsigned)(base + 3);
        }
    }

    // ---- End drain: queue -> per-lane lists (each entry inserted once) ----
    {
        const unsigned n = wcnt[wave];
        for (unsigned o = lane; o < n; o += 64) sort_insert(loc, qq[wave][o]);
    }

    // ---- Verified block merge (byte-identical tree) + output ----
    __syncthreads();                     // everyone past bootstrap-tree reads of sk
    #pragma unroll
    for (int j = 0; j < KSEL; ++j) sk[t * KSEL + j] = loc[j];
    __syncthreads();
    for (int s = NTHREADS / 2; s > 0; s >>= 1) {
        if (t < s) {
            ull a[KSEL], bb[KSEL];
            #pragma unroll
            for (int j = 0; j < KSEL; ++j) { a[j] = sk[t * KSEL + j]; bb[j] = sk[(t + s) * KSEL + j]; }
            merge5(a, bb);
            #pragma unroll
            for (int j = 0; j < KSEL; ++j) sk[t * KSEL + j] = a[j];
        }
        __syncthreads();
    }

    if (t < KSEL) {
        keys_out[((size_t)bid * SPLIT + split) * KSEL + t] = sk[t];
    }
}

// Epilogue (verified, unchanged): merge the SPLIT partial top-5s per row, roll
// along L, min positional distance over the 5 selected pixels, mean.
__global__ __launch_bounds__(NTHREADS)
void finalize_kernel(const float* __restrict__ preds,
                     const ull* __restrict__ keys,
                     float* __restrict__ out) {
    const int t = threadIdx.x;
    float acc = 0.0f;

    for (int p = t; p < BS * LUSED; p += NTHREADS) {
        const int b = p / LUSED;
        const int l = p % LUSED + 1;              // loss rows: l = 1..63
        const float px = preds[b * (LL * 8) + l * 8 + 0];
        const float py = preds[b * (LL * 8) + l * 8 + 1];

        // tgt_down[:, l] = tgt[:, l-1]: merge the SPLIT sorted 5-lists of row l-1.
        const int srow = b * LL + (l - 1);
        ull loc[KSEL];
        #pragma unroll
        for (int j = 0; j < KSEL; ++j) loc[j] = SENTK;
        #pragma unroll
        for (int s = 0; s < SPLIT; ++s) {
            #pragma unroll
            for (int k = 0; k < KSEL; ++k) {
                sort_insert(loc, keys[((size_t)srow * SPLIT + s) * KSEL + k]);
            }
        }

        float best = 3.4028235e38f;
        #pragma unroll
        for (int k = 0; k < KSEL; ++k) {
            const int ixk = (int)(loc[k] & 0xFFFFFFFFULL);
            const float tx = (float)(ixk & 255) * (1.0f / 256.0f);   // exact /256
            const float ty = (float)(ixk >> 8) * (1.0f / 256.0f);
            const float dx = __fsub_rn(px, tx);
            const float dy = __fsub_rn(py, ty);
            const float dist = __fadd_rn(__fmul_rn(dx, dx), __fmul_rn(dy, dy));
            best = dist < best ? dist : best;
        }
        acc += best;
    }

    __shared__ float red[NTHREADS];
    red[t] = acc;
    __syncthreads();
    for (int s = NTHREADS / 2; s > 0; s >>= 1) {
        if (t < s) red[t] += red[t + s];
        __syncthreads();
    }
    if (t == 0) {
        out[0] = red[0] / (float)(BS * (LL - 1));
    }
}

extern "C" void kernel_launch(void* const* d_in, const int* in_sizes, int n_in,
                              void* d_out, int out_size, void* d_ws, size_t ws_size,
                              hipStream_t stream) {
    const float* preds = (const float*)d_in[0];   // (8, 64, 8) f32
    const float* imgs  = (const float*)d_in[1];   // (8, 3, 256, 256) f32
    float* out = (float*)d_out;                   // scalar f32
    ull* keys = (ull*)d_ws;                       // 512 * SPLIT * 5 u64 = 80 KB

    topk_kernel<<<dim3(BS * LUSED * SPLIT), dim3(NTHREADS), 0, stream>>>(preds, imgs, keys);
    finalize_kernel<<<dim3(1), dim3(NTHREADS), 0, stream>>>(preds, keys, out);
}

// Round 9
// 89.544 us; speedup vs baseline: 5.1696x; 1.0793x over previous
//
#include <hip/hip_runtime.h>

#define IMG_SIZE 256
#define NPIX (IMG_SIZE * IMG_SIZE)
#define KSEL 5
#define BS 8
#define LL 64
#define LUSED 63          // row l=63's top-k is discarded by the roll — never compute it
#define NTHREADS 256
#define SPLIT 4           // blocks per (b,l) row
#define CHUNK (NPIX / SPLIT)      // 16384 pixels per block
#define QCAP 320          // per-wave candidate queue; 4*QCAP*8 == NTHREADS*KSEL*8
#define SENTK 0xFFFFFFFFFFFFFFFFULL

typedef unsigned long long ull;

// Branchless sorted-insert: loc[] ascending; bubble key in, evict the max.
// Static indices only -> stays in VGPRs; no divergence.
__device__ __forceinline__ void sort_insert(ull loc[KSEL], ull key) {
    #pragma unroll
    for (int j = 0; j < KSEL; ++j) {
        const ull a = loc[j];
        const bool lt = key < a;
        loc[j] = lt ? key : a;
        key    = lt ? a : key;
    }
}

// Merge two ascending 5-lists, keep smallest 5 into a.
__device__ __forceinline__ void merge5(ull* a, const ull* b) {
    ull out[KSEL];
    int ia = 0, ib = 0;
    #pragma unroll
    for (int j = 0; j < KSEL; ++j) {
        const ull va = a[ia], vb = b[ib];
        const bool ta = va <= vb;
        out[j] = ta ? va : vb;
        ia += ta ? 1 : 0;
        ib += ta ? 0 : 1;
    }
    #pragma unroll
    for (int j = 0; j < KSEL; ++j) a[j] = out[j];
}

// Single source of truth for the SSD: match numpy f32 exactly — no FMA
// contraction, ((d0^2+d1^2)+d2^2). Both the bootstrap keys and the steady-path
// gate use THIS function, so gate-s and key-s are bit-identical.
__device__ __forceinline__ float
pix_s(float r0, float r1, float r2, float c0, float c1, float c2) {
    float d0 = __fsub_rn(r0, c0);
    float d1 = __fsub_rn(r1, c1);
    float d2 = __fsub_rn(r2, c2);
    return __fadd_rn(__fadd_rn(__fmul_rn(d0, d0), __fmul_rn(d1, d1)), __fmul_rn(d2, d2));
}

__device__ __forceinline__ ull
pix_key(float r0, float r1, float r2, float c0, float c1, float c2, int pix) {
    // s >= 0 (sum of squares) -> uint bit order == float order; low bits = pixel
    // index gives jax top_k's lower-index-first tie-break.
    const float s = pix_s(r0, r1, r2, c0, c1, c2);
    return ((ull)__float_as_uint(s) << 32) | (unsigned int)pix;
}

// One block per (b,l,split). R8 structure (verified, 96.6us): bootstrap 1024 px
// -> block-exact threshold -> gate-to-memory steady loop (9-op s test, rare
// LDS-queue push) -> drain -> verified merge tree.
// R8 counters showed the kernel latency/occupancy-bound (VALUBusy 35%, occ 39%,
// dur unchanged at 42us): LDS 27KB capped residency at ~3 blocks/CU. Fix here:
// sk (merge scratch) and qq (queues) have disjoint live ranges -> UNION them.
// LDS 27.1KB -> ~10.3KB; 8 blocks/CU -> all 2016 blocks co-resident (one
// residency round). No arithmetic change anywhere; exactness argument as R8:
//   thr = 5th-smallest s over the bootstrap subset >= s5_chunk;
//   admit iff bits(s) <= thr => every true top-5 key is in bootstrap ∪ queue;
//   each pixel enters exactly once => bit-identical top-5.
// Union safety: sk's bootstrap contents are dead once thr is in registers;
// qq is dead after the drain; wave w's sk slice (64 thr x 40 B = 2560 B) is
// exactly qq[w]'s 320x8 B region, and a barrier separates drain from sk writes.
__global__ __launch_bounds__(NTHREADS)
void topk_kernel(const float* __restrict__ preds,
                 const float* __restrict__ imgs,
                 ull* __restrict__ keys_out) {
    const int blk = blockIdx.x;
    const int split = blk & (SPLIT - 1);
    const int row = blk / SPLIT;         // 0 .. BS*LUSED-1
    const int b = row / LUSED;
    const int l = row % LUSED;
    const int bid = b * LL + l;          // storage row (l < 63)
    const int t = threadIdx.x;
    const int wave = t >> 6;
    const int lane = t & 63;

    __shared__ union ShMem {
        ull sk[NTHREADS * KSEL];         // 10240 B: merge scratch
        ull qq[4][QCAP];                 // 10240 B: per-wave candidate queues
    } shm;
    __shared__ unsigned wcnt[4];
    __shared__ unsigned thrsh;

    if (t < 4) wcnt[t] = 0u;

    // Scrambled pooled indexing: flat i = l*bs + b; position from preds[i//L, i%L].
    const int i = l * BS + b;
    const int pb = i >> 6;
    const int pl = i & 63;
    const float px = preds[pb * (LL * 8) + pl * 8 + 0];
    const float py = preds[pb * (LL * 8) + pl * 8 + 1];

    // grid_sample nearest, align_corners=False, zeros padding.
    const float cx = __fsub_rn(__fmul_rn(px, 256.0f), 0.5f);
    const float cy = __fsub_rn(__fmul_rn(py, 256.0f), 0.5f);
    const int ix = (int)rintf(cx);       // round half to even == jnp.rint
    const int iy = (int)rintf(cy);
    const bool valid = (ix >= 0) && (ix < IMG_SIZE) && (iy >= 0) && (iy < IMG_SIZE);
    const int ixc = min(max(ix, 0), IMG_SIZE - 1);
    const int iyc = min(max(iy, 0), IMG_SIZE - 1);
    const float vmul = valid ? 1.0f : 0.0f;

    const float* imgb = imgs + (size_t)b * 3 * NPIX;
    const float c0 = imgb[0 * NPIX + iyc * IMG_SIZE + ixc] * vmul;
    const float c1 = imgb[1 * NPIX + iyc * IMG_SIZE + ixc] * vmul;
    const float c2 = imgb[2 * NPIX + iyc * IMG_SIZE + ixc] * vmul;

    const float4* p0 = (const float4*)(imgb + 0 * NPIX);
    const float4* p1 = (const float4*)(imgb + 1 * NPIX);
    const float4* p2 = (const float4*)(imgb + 2 * NPIX);

    ull loc[KSEL];
    #pragma unroll
    for (int j = 0; j < KSEL; ++j) loc[j] = SENTK;

    const int v0 = split * (CHUNK / 4);

    // ---- Bootstrap: iteration 0 (1024 pixels), unconditional inserts ----
    {
        const int v = v0 + t;
        const float4 r0 = p0[v];
        const float4 r1 = p1[v];
        const float4 r2 = p2[v];
        const int base = v * 4;
        sort_insert(loc, pix_key(r0.x, r1.x, r2.x, c0, c1, c2, base + 0));
        sort_insert(loc, pix_key(r0.y, r1.y, r2.y, c0, c1, c2, base + 1));
        sort_insert(loc, pix_key(r0.z, r1.z, r2.z, c0, c1, c2, base + 2));
        sort_insert(loc, pix_key(r0.w, r1.w, r2.w, c0, c1, c2, base + 3));
    }

    // Block-exact bootstrap threshold via the verified merge5 tree.
    #pragma unroll
    for (int j = 0; j < KSEL; ++j) shm.sk[t * KSEL + j] = loc[j];
    __syncthreads();
    for (int s = NTHREADS / 2; s > 0; s >>= 1) {
        if (t < s) {
            ull a[KSEL], bb[KSEL];
            #pragma unroll
            for (int j = 0; j < KSEL; ++j) { a[j] = shm.sk[t * KSEL + j]; bb[j] = shm.sk[(t + s) * KSEL + j]; }
            merge5(a, bb);
            #pragma unroll
            for (int j = 0; j < KSEL; ++j) shm.sk[t * KSEL + j] = a[j];
        }
        __syncthreads();
    }
    if (t == 0) thrsh = (unsigned)(shm.sk[KSEL - 1] >> 32);   // bits of s5(bootstrap)
    __syncthreads();
    const unsigned thr = thrsh;          // register; sk contents now dead -> qq may reuse
    if (t < 4) wcnt[t] = 0u;             // (re-assert; qq region about to be used)
    __syncthreads();

    // ---- Steady loop: dense loads, 9-op s + gate, rare queue push ----
    #pragma unroll 2
    for (int it = 1; it < CHUNK / 4 / NTHREADS; ++it) {
        // Overflow safety (wave-uniform; never triggers on random data):
        // guarantee room for this iteration's max 256 pushes (wcnt <= 64 after).
        if (wcnt[wave] + NTHREADS > QCAP) {
            const unsigned n = wcnt[wave];
            for (unsigned o = lane; o < n; o += 64) sort_insert(loc, shm.qq[wave][o]);
            if (lane == 0) wcnt[wave] = 0u;   // per-wave LDS ops are in-order: reads precede
        }
        const int v = v0 + it * NTHREADS + t;
        const float4 r0 = p0[v];
        const float4 r1 = p1[v];
        const float4 r2 = p2[v];
        const int base = v * 4;

        const float sx = pix_s(r0.x, r1.x, r2.x, c0, c1, c2);
        const float sy = pix_s(r0.y, r1.y, r2.y, c0, c1, c2);
        const float sz = pix_s(r0.z, r1.z, r2.z, c0, c1, c2);
        const float sw = pix_s(r0.w, r1.w, r2.w, c0, c1, c2);

        if (__float_as_uint(sx) <= thr) {
            const unsigned pos = atomicAdd(&wcnt[wave], 1u);
            shm.qq[wave][pos] = ((ull)__float_as_uint(sx) << 32) | (unsigned)(base + 0);
        }
        if (__float_as_uint(sy) <= thr) {
            const unsigned pos = atomicAdd(&wcnt[wave], 1u);
            shm.qq[wave][pos] = ((ull)__float_as_uint(sy) << 32) | (unsigned)(base + 1);
        }
        if (__float_as_uint(sz) <= thr) {
            const unsigned pos = atomicAdd(&wcnt[wave], 1u);
            shm.qq[wave][pos] = ((ull)__float_as_uint(sz) << 32) | (unsigned)(base + 2);
        }
        if (__float_as_uint(sw) <= thr) {
            const unsigned pos = atomicAdd(&wcnt[wave], 1u);
            shm.qq[wave][pos] = ((ull)__float_as_uint(sw) << 32) | (unsigned)(base + 3);
        }
    }

    // ---- End drain: queue -> per-lane lists (each entry inserted once) ----
    {
        const unsigned n = wcnt[wave];
        for (unsigned o = lane; o < n; o += 64) sort_insert(loc, shm.qq[wave][o]);
    }

    // ---- Verified block merge (byte-identical tree) + output ----
    __syncthreads();                     // all waves done draining before sk reuse
    #pragma unroll
    for (int j = 0; j < KSEL; ++j) shm.sk[t * KSEL + j] = loc[j];
    __syncthreads();
    for (int s = NTHREADS / 2; s > 0; s >>= 1) {
        if (t < s) {
            ull a[KSEL], bb[KSEL];
            #pragma unroll
            for (int j = 0; j < KSEL; ++j) { a[j] = shm.sk[t * KSEL + j]; bb[j] = shm.sk[(t + s) * KSEL + j]; }
            merge5(a, bb);
            #pragma unroll
            for (int j = 0; j < KSEL; ++j) shm.sk[t * KSEL + j] = a[j];
        }
        __syncthreads();
    }

    if (t < KSEL) {
        keys_out[((size_t)bid * SPLIT + split) * KSEL + t] = shm.sk[t];
    }
}

// Epilogue (verified, unchanged): merge the SPLIT partial top-5s per row, roll
// along L, min positional distance over the 5 selected pixels, mean.
__global__ __launch_bounds__(NTHREADS)
void finalize_kernel(const float* __restrict__ preds,
                     const ull* __restrict__ keys,
                     float* __restrict__ out) {
    const int t = threadIdx.x;
    float acc = 0.0f;

    for (int p = t; p < BS * LUSED; p += NTHREADS) {
        const int b = p / LUSED;
        const int l = p % LUSED + 1;              // loss rows: l = 1..63
        const float px = preds[b * (LL * 8) + l * 8 + 0];
        const float py = preds[b * (LL * 8) + l * 8 + 1];

        // tgt_down[:, l] = tgt[:, l-1]: merge the SPLIT sorted 5-lists of row l-1.
        const int srow = b * LL + (l - 1);
        ull loc[KSEL];
        #pragma unroll
        for (int j = 0; j < KSEL; ++j) loc[j] = SENTK;
        #pragma unroll
        for (int s = 0; s < SPLIT; ++s) {
            #pragma unroll
            for (int k = 0; k < KSEL; ++k) {
                sort_insert(loc, keys[((size_t)srow * SPLIT + s) * KSEL + k]);
            }
        }

        float best = 3.4028235e38f;
        #pragma unroll
        for (int k = 0; k < KSEL; ++k) {
            const int ixk = (int)(loc[k] & 0xFFFFFFFFULL);
            const float tx = (float)(ixk & 255) * (1.0f / 256.0f);   // exact /256
            const float ty = (float)(ixk >> 8) * (1.0f / 256.0f);
            const float dx = __fsub_rn(px, tx);
            const float dy = __fsub_rn(py, ty);
            const float dist = __fadd_rn(__fmul_rn(dx, dx), __fmul_rn(dy, dy));
            best = dist < best ? dist : best;
        }
        acc += best;
    }

    __shared__ float red[NTHREADS];
    red[t] = acc;
    __syncthreads();
    for (int s = NTHREADS / 2; s > 0; s >>= 1) {
        if (t < s) red[t] += red[t + s];
        __syncthreads();
    }
    if (t == 0) {
        out[0] = red[0] / (float)(BS * (LL - 1));
    }
}

extern "C" void kernel_launch(void* const* d_in, const int* in_sizes, int n_in,
                              void* d_out, int out_size, void* d_ws, size_t ws_size,
                              hipStream_t stream) {
    const float* preds = (const float*)d_in[0];   // (8, 64, 8) f32
    const float* imgs  = (const float*)d_in[1];   // (8, 3, 256, 256) f32
    float* out = (float*)d_out;                   // scalar f32
    ull* keys = (ull*)d_ws;                       // 512 * SPLIT * 5 u64 = 80 KB

    topk_kernel<<<dim3(BS * LUSED * SPLIT), dim3(NTHREADS), 0, stream>>>(preds, imgs, keys);
    finalize_kernel<<<dim3(1), dim3(NTHREADS), 0, stream>>>(preds, keys, out);
}